// Round 1
// baseline (346.267 us; speedup 1.0000x reference)
//
#include <hip/hip_runtime.h>
#include <math.h>

// 2D inverse DFT (+i sign, 1/N^2 scale) of 64 x 512 x 512 complex, then magnitude.
// Pass 1: IFFT along Y (column groups of 8 x), pass 2: IFFT along X (rows) + |z|.

__device__ __forceinline__ float2 cmul(float2 a, float2 b) {
    return make_float2(a.x * b.x - a.y * b.y, a.x * b.y + a.y * b.x);
}
__device__ __forceinline__ float2 cadd(float2 a, float2 b) { return make_float2(a.x + b.x, a.y + b.y); }
__device__ __forceinline__ float2 csub(float2 a, float2 b) { return make_float2(a.x - b.x, a.y - b.y); }
__device__ __forceinline__ unsigned rev9(unsigned v) { return __brev(v) >> 23; }

#define TWO_PI_F 6.283185307179586f

// Pass 1: IFFT along Y for a group of 8 consecutive x, one b.
// grid = (512/8, 64) = (64, 64), block = 256.
__global__ __launch_bounds__(256)
void fft_y_kernel(const float2* __restrict__ in, float2* __restrict__ ws) {
    __shared__ float2 tile[512][8];   // 32 KiB
    __shared__ float2 tw[256];        // 2 KiB: tw[j] = exp(+2*pi*i*j/512)
    const int t  = threadIdx.x;
    const int g  = t & 7;        // column within group
    const int ty = t >> 3;       // 0..31
    const int x0 = blockIdx.x * 8;
    const int b  = blockIdx.y;

    {
        float s, c;
        sincosf(TWO_PI_F * (float)t * (1.0f / 512.0f), &s, &c);
        tw[t] = make_float2(c, s);
    }

    const float2* src = in + ((size_t)b << 18) + x0;   // b*512*512 + x0
    // load 512 y x 8 g, bit-reversed into LDS (DIT)
    for (int it = 0; it < 16; ++it) {
        int y = (it << 5) + ty;
        tile[rev9((unsigned)y)][g] = src[((size_t)y << 9) + g];
    }
    __syncthreads();

    // 9 radix-2 DIT stages; 256 butterflies/column/stage, 32 threads/column -> 8 each
    for (int s = 1; s <= 9; ++s) {
        const int half = 1 << (s - 1);
        for (int k = 0; k < 8; ++k) {
            const int bi  = ty + (k << 5);            // 0..255
            const int j   = bi & (half - 1);
            const int pos = ((bi >> (s - 1)) << s) + j;
            const float2 w = tw[j << (9 - s)];
            const float2 u = tile[pos][g];
            const float2 v = cmul(w, tile[pos + half][g]);
            tile[pos][g]        = cadd(u, v);
            tile[pos + half][g] = csub(u, v);
        }
        __syncthreads();
    }

    float2* dst = ws + ((size_t)b << 18) + x0;
    for (int it = 0; it < 16; ++it) {
        int y = (it << 5) + ty;
        dst[((size_t)y << 9) + g] = tile[y][g];
    }
}

// Pass 2: IFFT along X per row + magnitude, 8 rows serially per block.
// grid = (512/8, 64) = (64, 64), block = 256.
__global__ __launch_bounds__(256)
void fft_x_mag_kernel(const float2* __restrict__ ws, float* __restrict__ out) {
    __shared__ float2 tile[512];  // 4 KiB
    __shared__ float2 tw[256];    // 2 KiB
    const int t  = threadIdx.x;
    const int b  = blockIdx.y;
    const int y0 = blockIdx.x * 8;

    {
        float s, c;
        sincosf(TWO_PI_F * (float)t * (1.0f / 512.0f), &s, &c);
        tw[t] = make_float2(c, s);
    }
    __syncthreads();

    for (int r = 0; r < 8; ++r) {
        const int y = y0 + r;
        const float2* src = ws + (size_t)(b * 512 + y) * 512;
        tile[rev9((unsigned)t)]       = src[t];
        tile[rev9((unsigned)(t + 256))] = src[t + 256];
        __syncthreads();

        for (int s = 1; s <= 9; ++s) {
            const int half = 1 << (s - 1);
            const int j    = t & (half - 1);
            const int pos  = ((t >> (s - 1)) << s) + j;
            const float2 w = tw[j << (9 - s)];
            const float2 u = tile[pos];
            const float2 v = cmul(w, tile[pos + half]);
            tile[pos]        = cadd(u, v);
            tile[pos + half] = csub(u, v);
            __syncthreads();
        }

        float* orow = out + (size_t)(b * 512 + y) * 512;
        const float2 z0 = tile[t];
        const float2 z1 = tile[t + 256];
        orow[t]       = sqrtf(z0.x * z0.x + z0.y * z0.y) * (1.0f / 262144.0f);
        orow[t + 256] = sqrtf(z1.x * z1.x + z1.y * z1.y) * (1.0f / 262144.0f);
        __syncthreads();   // protect tile before next row's load
    }
}

extern "C" void kernel_launch(void* const* d_in, const int* in_sizes, int n_in,
                              void* d_out, int out_size, void* d_ws, size_t ws_size,
                              hipStream_t stream) {
    const float2* in = (const float2*)d_in[0];
    float2* ws = (float2*)d_ws;          // needs 64*512*512*8 = 128 MiB
    float* out = (float*)d_out;

    fft_y_kernel<<<dim3(64, 64), 256, 0, stream>>>(in, ws);
    fft_x_mag_kernel<<<dim3(64, 64), 256, 0, stream>>>(ws, out);
}

// Round 2
// 294.629 us; speedup vs baseline: 1.1753x; 1.1753x over previous
//
#include <hip/hip_runtime.h>
#include <math.h>

// 2D inverse DFT (+i sign, 1/512^2 scale) of 64 x 512 x 512 complex, then |.|.
// Register-resident 512-pt FFT per wave: 8 complex/lane (i = k*64 + lane).
// DIF: 3 register stages (stride 256/128/64) + 6 shuffle stages (32..1).
// Output lands bit-reversed; Y-reversal is deferred to pass-2 row indexing,
// X-reversal is resolved in pass-2 store addressing.

#define TWO_PI_F 6.283185307179586f

__device__ __forceinline__ float2 cmul(float2 a, float2 b) {
    return make_float2(a.x * b.x - a.y * b.y, a.x * b.y + a.y * b.x);
}
__device__ __forceinline__ float2 cadd(float2 a, float2 b) { return make_float2(a.x + b.x, a.y + b.y); }
__device__ __forceinline__ float2 csub(float2 a, float2 b) { return make_float2(a.x - b.x, a.y - b.y); }
__device__ __forceinline__ float2 csq(float2 a) { return make_float2(a.x * a.x - a.y * a.y, 2.f * a.x * a.y); }
__device__ __forceinline__ unsigned rev9(unsigned v) { return __brev(v) >> 23; }
__device__ __forceinline__ unsigned rev6(unsigned v) { return __brev(v) >> 26; }

// In-place 512-pt inverse-sign DIF FFT. Lane l, regs k: element i = k*64 + l.
// On exit, position i holds X[rev9(i)]. A = exp(+2*pi*i*l/512).
__device__ __forceinline__ void fft512(float2* r, float2 A, int l) {
    const float S = 0.70710678118654752f;
    // stage d=256: pairs (k, k+4); w = A * exp(2*pi*i*k/8)
    {
        float2 t0 = A;
        float2 t1 = cmul(A, make_float2(S, S));
        float2 t2 = make_float2(-A.y, A.x);
        float2 t3 = cmul(A, make_float2(-S, S));
        float2 u, v;
        u = r[0]; v = r[4]; r[0] = cadd(u, v); r[4] = cmul(csub(u, v), t0);
        u = r[1]; v = r[5]; r[1] = cadd(u, v); r[5] = cmul(csub(u, v), t1);
        u = r[2]; v = r[6]; r[2] = cadd(u, v); r[6] = cmul(csub(u, v), t2);
        u = r[3]; v = r[7]; r[3] = cadd(u, v); r[7] = cmul(csub(u, v), t3);
    }
    // stage d=128: pairs (k, k+2); w = A^2 * {1, i}
    float2 A2 = csq(A);
    {
        float2 A2i = make_float2(-A2.y, A2.x);
        float2 u, v;
        u = r[0]; v = r[2]; r[0] = cadd(u, v); r[2] = cmul(csub(u, v), A2);
        u = r[1]; v = r[3]; r[1] = cadd(u, v); r[3] = cmul(csub(u, v), A2i);
        u = r[4]; v = r[6]; r[4] = cadd(u, v); r[6] = cmul(csub(u, v), A2);
        u = r[5]; v = r[7]; r[5] = cadd(u, v); r[7] = cmul(csub(u, v), A2i);
    }
    // stage d=64: pairs (k, k+1); w = A^4
    float2 A4 = csq(A2);
    {
        float2 u, v;
        u = r[0]; v = r[1]; r[0] = cadd(u, v); r[1] = cmul(csub(u, v), A4);
        u = r[2]; v = r[3]; r[2] = cadd(u, v); r[3] = cmul(csub(u, v), A4);
        u = r[4]; v = r[5]; r[4] = cadd(u, v); r[5] = cmul(csub(u, v), A4);
        u = r[6]; v = r[7]; r[6] = cadd(u, v); r[7] = cmul(csub(u, v), A4);
    }
    // shuffle stages m = 32,16,8,4,2,1: w = -P on active lanes, P = A^(256/m).
    // active lane: r = (own - other) * P ; passive: r = own + other.
    float2 P = csq(A4);  // A^8
    #pragma unroll
    for (int mi = 0; mi < 6; ++mi) {
        const int m = 32 >> mi;
        const bool hi = (l & m) != 0;
        #pragma unroll
        for (int k = 0; k < 8; ++k) {
            float2 o;
            o.x = __shfl_xor(r[k].x, m);
            o.y = __shfl_xor(r[k].y, m);
            float2 sum = cadd(r[k], o);
            float2 dif = cmul(csub(r[k], o), P);
            r[k].x = hi ? dif.x : sum.x;
            r[k].y = hi ? dif.y : sum.y;
        }
        if (mi < 5) P = csq(P);
    }
}

// Pass 1: IFFT along Y. Block = 512 thr (8 waves), 8 columns; wave w owns col w.
// grid = (64, 64). LDS tile XOR-swizzled; 2 barriers total.
__global__ __launch_bounds__(512)
void fft_y_kernel(const float2* __restrict__ in, float2* __restrict__ ws) {
    __shared__ float2 tile[4096];  // [y=512][col=8], col swizzled: 32 KiB
    const int t = threadIdx.x;
    const int w = t >> 6, l = t & 63;
    const int g = t & 7, q = t >> 3;       // staging coords
    const int x0 = blockIdx.x * 8;
    const int b = blockIdx.y;

    const float2* src = in + ((size_t)b << 18) + x0;
    const int sw = (q & 7) ^ ((q >> 3) & 7);   // swizzle for y with y%64==q
    #pragma unroll
    for (int it = 0; it < 8; ++it) {
        const int y = it * 64 + q;
        tile[y * 8 + (g ^ sw)] = src[((size_t)y << 9) + g];
    }
    __syncthreads();

    float sA, cA;
    sincosf(TWO_PI_F * (float)l * (1.0f / 512.0f), &sA, &cA);
    float2 r[8];
    const int swl = (l & 7) ^ ((l >> 3) & 7);
    #pragma unroll
    for (int k = 0; k < 8; ++k)
        r[k] = tile[(k * 64 + l) * 8 + (w ^ swl)];

    fft512(r, make_float2(cA, sA), l);

    // column w is wave-private: no barrier needed between read and write-back
    #pragma unroll
    for (int k = 0; k < 8; ++k)
        tile[(k * 64 + l) * 8 + (w ^ swl)] = r[k];
    __syncthreads();

    // ws row i holds Y-frequency rev9(i); pass 2 compensates in its row index.
    float2* dst = ws + ((size_t)b << 18) + x0;
    #pragma unroll
    for (int it = 0; it < 8; ++it) {
        const int y = it * 64 + q;
        dst[((size_t)y << 9) + g] = tile[y * 8 + (g ^ sw)];
    }
}

// Pass 2: IFFT along X per row + magnitude. Block = 256 thr (4 waves, 4 rows),
// no LDS, no barriers. grid = 32768/4 = 8192.
__global__ __launch_bounds__(256)
void fft_x_mag_kernel(const float2* __restrict__ ws, float* __restrict__ out) {
    const int t = threadIdx.x;
    const int w = t >> 6, l = t & 63;
    const int row = blockIdx.x * 4 + w;       // 0..32767
    const int b = row >> 9, ry = row & 511;

    const float2* src = ws + ((size_t)row << 9);
    float2 r[8];
    #pragma unroll
    for (int k = 0; k < 8; ++k)
        r[k] = src[k * 64 + l];

    float sA, cA;
    sincosf(TWO_PI_F * (float)l * (1.0f / 512.0f), &sA, &cA);
    fft512(r, make_float2(cA, sA), l);

    // r[k] holds X-freq rev9(k*64+l) = rev6(l)*8 + rev3(k): lane l owns the 8
    // contiguous output floats at base rev6(l)*8.
    const int rev3k[8] = {0, 4, 2, 6, 1, 5, 3, 7};
    float m[8];
    #pragma unroll
    for (int k = 0; k < 8; ++k) {
        const float2 z = r[k];
        m[rev3k[k]] = sqrtf(z.x * z.x + z.y * z.y) * (1.0f / 262144.0f);
    }

    // this ws row holds Y-frequency rev9(ry) -> output row rev9(ry)
    float* orow = out + (((size_t)(b << 9) + rev9(ry)) << 9);
    const int base = rev6(l) * 8;
    *(float4*)(orow + base)     = make_float4(m[0], m[1], m[2], m[3]);
    *(float4*)(orow + base + 4) = make_float4(m[4], m[5], m[6], m[7]);
}

extern "C" void kernel_launch(void* const* d_in, const int* in_sizes, int n_in,
                              void* d_out, int out_size, void* d_ws, size_t ws_size,
                              hipStream_t stream) {
    const float2* in = (const float2*)d_in[0];
    float2* ws = (float2*)d_ws;   // 64*512*512*8 = 128 MiB
    float* out = (float*)d_out;

    fft_y_kernel<<<dim3(64, 64), 512, 0, stream>>>(in, ws);
    fft_x_mag_kernel<<<8192, 256, 0, stream>>>(ws, out);
}